// Round 1
// baseline (3996.666 us; speedup 1.0000x reference)
//
#include <hip/hip_runtime.h>
#include <math.h>

#define BM 64
#define BN 64
#define BK 16
#define EDGES 800000
#define NNODES 100000
#define NGRAPH 1024

// ---------------- edge scatter: agg[dst] += x[src] ----------------
__global__ __launch_bounds__(256) void scatter_add_k(
    const float* __restrict__ X, const int* __restrict__ src,
    const int* __restrict__ dst, float* __restrict__ agg, int E_, int F) {
  int t = blockIdx.x * 256 + threadIdx.x;
  int e = t >> 5;
  int lane = t & 31;
  if (e >= E_) return;
  int s = src[e], d = dst[e];
  const float* xs = X + (long)s * F;
  float* ad = agg + (long)d * F;
  for (int f = lane; f < F; f += 32) atomicAdd(&ad[f], xs[f]);
}

// ---------------- tiled f32 GEMM: C = act((A0[+A1]) @ W + bias) ----------------
// EPI: 0 = relu + store, 1 = store (no act), 2 = relu + fused segment pool (sum+max)
template <int EPI>
__global__ __launch_bounds__(256) void gemm_k(
    const float* __restrict__ A0, const float* __restrict__ A1,
    const float* __restrict__ W, const float* __restrict__ bias,
    float* __restrict__ C, int M, int K, int Nc, int ldc,
    const int* __restrict__ bat, float* __restrict__ pool, int NCpool) {
  __shared__ __align__(16) float As[BK][BM + 4];
  __shared__ __align__(16) float Bs[BK][BN + 4];
  int tid = threadIdx.x;
  int tx = tid & 15, ty = tid >> 4;
  int row0 = blockIdx.y * BM, col0 = blockIdx.x * BN;
  float acc[4][4] = {};

  for (int k0 = 0; k0 < K; k0 += BK) {
#pragma unroll
    for (int i = 0; i < 4; ++i) {
      int e = tid + 256 * i;
      int r = e >> 4, k = e & 15;
      int gr = row0 + r, gk = k0 + k;
      float v = 0.f;
      if (gr < M && gk < K) {
        v = A0[(long)gr * K + gk];
        if (A1) v += A1[(long)gr * K + gk];
      }
      As[k][r] = v;
    }
#pragma unroll
    for (int i = 0; i < 4; ++i) {
      int e = tid + 256 * i;
      int k = e >> 6, c = e & 63;
      int gk = k0 + k, gc = col0 + c;
      Bs[k][c] = (gk < K && gc < Nc) ? W[(long)gk * Nc + gc] : 0.f;
    }
    __syncthreads();
#pragma unroll
    for (int k = 0; k < BK; ++k) {
      float4 a = *reinterpret_cast<const float4*>(&As[k][ty * 4]);
      float4 b = *reinterpret_cast<const float4*>(&Bs[k][tx * 4]);
      float av[4] = {a.x, a.y, a.z, a.w};
      float bv[4] = {b.x, b.y, b.z, b.w};
#pragma unroll
      for (int i = 0; i < 4; ++i)
#pragma unroll
        for (int j = 0; j < 4; ++j) acc[i][j] += av[i] * bv[j];
    }
    __syncthreads();
  }

  if constexpr (EPI == 0 || EPI == 1) {
#pragma unroll
    for (int i = 0; i < 4; ++i) {
      int gr = row0 + ty * 4 + i;
      if (gr >= M) continue;
#pragma unroll
      for (int j = 0; j < 4; ++j) {
        int gc = col0 + tx * 4 + j;
        if (gc >= Nc) continue;
        float v = acc[i][j] + bias[gc];
        if (EPI == 0) v = fmaxf(v, 0.f);
        C[(long)gr * ldc + gc] = v;
      }
    }
  } else {
    // fused mean/max pool epilogue (batch ids sorted -> segmented reduce)
    __shared__ __align__(16) float Ct[BM][BN + 4];
    __shared__ int gid[BM];
    if (tid < BM) {
      int gr = row0 + tid;
      gid[tid] = (gr < M) ? bat[gr] : -1;
    }
#pragma unroll
    for (int i = 0; i < 4; ++i)
#pragma unroll
      for (int j = 0; j < 4; ++j) {
        int gc = col0 + tx * 4 + j;
        float v = acc[i][j] + ((gc < Nc) ? bias[gc] : 0.f);
        Ct[ty * 4 + i][tx * 4 + j] = fmaxf(v, 0.f);
      }
    __syncthreads();
    int c = tid & 63, grp = tid >> 6;
    int gc = col0 + c;
    if (gc < Nc) {
      float s = 0.f, mx = 0.f;
      int cur = -1;
      bool has = false;
      for (int r = grp * 16; r < grp * 16 + 16; ++r) {
        int g = gid[r];
        if (g != cur) {
          if (has) {
            atomicAdd(&pool[(long)cur * 2 * NCpool + gc], s);
            atomicMax((unsigned int*)&pool[(long)cur * 2 * NCpool + NCpool + gc],
                      __float_as_uint(mx));
          }
          cur = g;
          s = 0.f;
          mx = 0.f;
          has = (g >= 0);
        }
        if (g >= 0) {
          float v = Ct[r][c];
          s += v;
          mx = fmaxf(mx, v);
        }
      }
      if (has) {
        atomicAdd(&pool[(long)cur * 2 * NCpool + gc], s);
        atomicMax((unsigned int*)&pool[(long)cur * 2 * NCpool + NCpool + gc],
                  __float_as_uint(mx));
      }
    }
  }
}

// ---------------- small helper kernels ----------------
__global__ void count_k(const int* __restrict__ bat, float* __restrict__ cnt, int n) {
  int i = blockIdx.x * 256 + threadIdx.x;
  if (i < n) atomicAdd(&cnt[bat[i]], 1.f);
}

__global__ void mean_fin_k(float* __restrict__ pool, const float* __restrict__ cnt,
                           int Bn, int NC) {
  int idx = blockIdx.x * 256 + threadIdx.x;
  if (idx >= Bn * NC) return;
  int g = idx / NC, c = idx % NC;
  pool[(long)g * 2 * NC + c] /= fmaxf(cnt[g], 1.f);
}

__global__ void colmean_k(const float* __restrict__ X, float* __restrict__ cm,
                          int Rows, int Cols) {
  int j = blockIdx.x * 256 + threadIdx.x;
  if (j >= Cols) return;
  float s = 0.f;
  for (int r = 0; r < Rows; ++r) s += X[(long)r * Cols + j];
  cm[j] = s / Rows;
}

__global__ void ssq_k(const float* __restrict__ X, const float* __restrict__ cm,
                      float* __restrict__ ssq, int Rows, int Cols) {
  long total = (long)Rows * Cols;
  long stride = (long)gridDim.x * 256;
  float s = 0.f;
  for (long idx = (long)blockIdx.x * 256 + threadIdx.x; idx < total; idx += stride) {
    int c = (int)(idx % Cols);
    float d = X[idx] - cm[c];
    s += d * d;
  }
  for (int off = 32; off > 0; off >>= 1) s += __shfl_down(s, off);
  if ((threadIdx.x & 63) == 0) atomicAdd(ssq, s);
}

__global__ void pn_apply_k(float* __restrict__ X, const float* __restrict__ cm,
                           const float* __restrict__ ssq, int Rows, int Cols) {
  long idx = (long)blockIdx.x * 256 + threadIdx.x;
  if (idx >= (long)Rows * Cols) return;
  int c = (int)(idx % Cols);
  float scale = 1.f / sqrtf(1e-5f + ssq[0] / Rows);
  X[idx] = (X[idx] - cm[c]) * scale;
}

__global__ void bn_stats_k(const float* __restrict__ X, float* __restrict__ mu,
                           float* __restrict__ var, int Rows, int Cols) {
  int j = blockIdx.x * blockDim.x + threadIdx.x;
  if (j >= Cols) return;
  float s = 0.f, s2 = 0.f;
  for (int r = 0; r < Rows; ++r) {
    float v = X[(long)r * Cols + j];
    s += v;
    s2 += v * v;
  }
  float m = s / Rows;
  mu[j] = m;
  var[j] = s2 / Rows - m * m;
}

__global__ void bn_apply_k(float* __restrict__ X, const float* __restrict__ mu,
                           const float* __restrict__ var, const float* __restrict__ g,
                           const float* __restrict__ b, int Rows, int Cols) {
  long idx = (long)blockIdx.x * 256 + threadIdx.x;
  if (idx >= (long)Rows * Cols) return;
  int c = (int)(idx % Cols);
  X[idx] = (X[idx] - mu[c]) / sqrtf(var[c] + 1e-5f) * g[c] + b[c];
}

__global__ __launch_bounds__(64) void ff2_k(const float* __restrict__ Z,
                                            const float* __restrict__ W2,
                                            const float* __restrict__ b2,
                                            float* __restrict__ alpha,
                                            float* __restrict__ beta, int K) {
  int row = blockIdx.x;
  int t = threadIdx.x;
  float s0 = 0.f, s1 = 0.f;
  for (int k = t; k < K; k += 64) {
    float z = Z[(long)row * K + k];
    s0 += z * W2[2 * k];
    s1 += z * W2[2 * k + 1];
  }
  for (int off = 32; off > 0; off >>= 1) {
    s0 += __shfl_down(s0, off);
    s1 += __shfl_down(s1, off);
  }
  if (t == 0) {
    alpha[row] = 1.f / (1.f + expf(-(s0 + b2[0])));
    beta[row] = 1.f / (1.f + expf(-(s1 + b2[1])));
  }
}

// ---------------- branch driver ----------------
static void run_branch(const float* x, const int* ei, const int* bat,
                       const float* wc1, const float* bc1, const float* wc2,
                       const float* bc2, const float* fgw1, const float* fgb1,
                       const float* fgw2, const float* fgb2, const float* fgg,
                       const float* fgbt, const float* ffw1, const float* ffb1,
                       const float* ffw2, const float* ffb2, int N, int F,
                       float* out_alpha, float* out_beta, float* out_xg, float* AGG,
                       float* H, float* POOL, float* CNT, float* CM, float* MU,
                       float* VAR, float* SSQ, float* G1, float* Z1,
                       hipStream_t stream) {
  const int NC = F * 10;
  const int Bn = NGRAPH;
  const int* src = ei;
  const int* dst = ei + EDGES;

  // conv1: h = relu((x + agg) @ wc1 + bc1)
  hipMemsetAsync(AGG, 0, (size_t)N * F * 4, stream);
  scatter_add_k<<<(EDGES * 32 + 255) / 256, 256, 0, stream>>>(x, src, dst, AGG, EDGES, F);
  dim3 g1((F + 63) / 64, (N + 63) / 64);
  gemm_k<0><<<g1, 256, 0, stream>>>(x, AGG, wc1, bc1, H, N, F, F, F, nullptr, nullptr, 0);

  // conv2 + fused pool
  hipMemsetAsync(AGG, 0, (size_t)N * F * 4, stream);
  scatter_add_k<<<(EDGES * 32 + 255) / 256, 256, 0, stream>>>(H, src, dst, AGG, EDGES, F);
  hipMemsetAsync(POOL, 0, (size_t)Bn * 2 * NC * 4, stream);
  hipMemsetAsync(CNT, 0, Bn * 4, stream);
  dim3 g2((NC + 63) / 64, (N + 63) / 64);
  gemm_k<2><<<g2, 256, 0, stream>>>(H, AGG, wc2, bc2, nullptr, N, F, NC, 0, bat, POOL, NC);
  count_k<<<(N + 255) / 256, 256, 0, stream>>>(bat, CNT, N);
  mean_fin_k<<<(Bn * NC + 255) / 256, 256, 0, stream>>>(POOL, CNT, Bn, NC);

  // pairnorm on [Bn, 2*NC]
  int Cols = 2 * NC;
  colmean_k<<<(Cols + 255) / 256, 256, 0, stream>>>(POOL, CM, Bn, Cols);
  hipMemsetAsync(SSQ, 0, 4, stream);
  ssq_k<<<512, 256, 0, stream>>>(POOL, CM, SSQ, Bn, Cols);
  pn_apply_k<<<((long)Bn * Cols + 255) / 256, 256, 0, stream>>>(POOL, CM, SSQ, Bn, Cols);

  // FC1 relu
  dim3 gf1(1024 / 64, Bn / 64);
  gemm_k<0><<<gf1, 256, 0, stream>>>(POOL, nullptr, fgw1, fgb1, G1, Bn, Cols, 1024, 1024,
                                     nullptr, nullptr, 0);
  // FC2 (no act) -> xg slot in d_out
  dim3 gf2(512 / 64, Bn / 64);
  gemm_k<1><<<gf2, 256, 0, stream>>>(G1, nullptr, fgw2, fgb2, out_xg, Bn, 1024, 512, 512,
                                     nullptr, nullptr, 0);
  // batchnorm in place
  bn_stats_k<<<2, 256, 0, stream>>>(out_xg, MU, VAR, Bn, 512);
  bn_apply_k<<<(Bn * 512 + 255) / 256, 256, 0, stream>>>(out_xg, MU, VAR, fgg, fgbt, Bn, 512);
  // FF1 relu
  dim3 gff(256 / 64, Bn / 64);
  gemm_k<0><<<gff, 256, 0, stream>>>(out_xg, nullptr, ffw1, ffb1, Z1, Bn, 512, 256, 256,
                                     nullptr, nullptr, 0);
  // FF2 + sigmoid -> alpha, beta
  ff2_k<<<Bn, 64, 0, stream>>>(Z1, ffw2, ffb2, out_alpha, out_beta, 256);
}

extern "C" void kernel_launch(void* const* d_in, const int* in_sizes, int n_in,
                              void* d_out, int out_size, void* d_ws, size_t ws_size,
                              hipStream_t stream) {
  if (n_in < 34) return;
  const float* x0 = (const float*)d_in[0];
  const int* ei0 = (const int*)d_in[1];
  const int* b0 = (const int*)d_in[2];
  const float* x1 = (const float*)d_in[3];
  const int* ei1 = (const int*)d_in[4];
  const int* b1 = (const int*)d_in[5];
  const float* w_c1 = (const float*)d_in[6];
  const float* b_c1 = (const float*)d_in[7];
  const float* w_c2 = (const float*)d_in[8];
  const float* b_c2 = (const float*)d_in[9];
  const float* w_c3 = (const float*)d_in[10];
  const float* b_c3 = (const float*)d_in[11];
  const float* w_c4 = (const float*)d_in[12];
  const float* b_c4 = (const float*)d_in[13];
  const float* fg0_w1 = (const float*)d_in[14];
  const float* fg0_b1 = (const float*)d_in[15];
  const float* fg0_w2 = (const float*)d_in[16];
  const float* fg0_b2 = (const float*)d_in[17];
  const float* fg0_g = (const float*)d_in[18];
  const float* fg0_bt = (const float*)d_in[19];
  const float* fg1_w1 = (const float*)d_in[20];
  const float* fg1_b1 = (const float*)d_in[21];
  const float* fg1_w2 = (const float*)d_in[22];
  const float* fg1_b2 = (const float*)d_in[23];
  const float* fg1_g = (const float*)d_in[24];
  const float* fg1_bt = (const float*)d_in[25];
  const float* ff0_w1 = (const float*)d_in[26];
  const float* ff0_b1 = (const float*)d_in[27];
  const float* ff0_w2 = (const float*)d_in[28];
  const float* ff0_b2 = (const float*)d_in[29];
  const float* ff1_w1 = (const float*)d_in[30];
  const float* ff1_b1 = (const float*)d_in[31];
  const float* ff1_w2 = (const float*)d_in[32];
  const float* ff1_b2 = (const float*)d_in[33];

  float* out = (float*)d_out;
  float* alpha = out;
  float* beta = out + 1024;
  float* xg0 = out + 2048;
  float* xg1 = out + 2048 + 1024 * 512;
  float* alpha1 = out + 2048 + 2 * 1024 * 512;
  float* beta1 = alpha1 + 1024;

  char* w = (char*)d_ws;
  auto alloc = [&](size_t bytes) -> void* {
    void* p = (void*)w;
    w += ((bytes + 255) / 256) * 256;
    return p;
  };
  float* AGG = (float*)alloc((size_t)NNODES * 93 * 4);
  float* H = (float*)alloc((size_t)NNODES * 93 * 4);
  float* POOL = (float*)alloc((size_t)NGRAPH * 1860 * 4);
  float* CNT = (float*)alloc(NGRAPH * 4);
  float* CM = (float*)alloc(1860 * 4);
  float* MU = (float*)alloc(512 * 4);
  float* VAR = (float*)alloc(512 * 4);
  float* SSQ = (float*)alloc(256);
  float* G1 = (float*)alloc((size_t)NGRAPH * 1024 * 4);
  float* Z1 = (float*)alloc((size_t)NGRAPH * 256 * 4);
  if ((size_t)(w - (char*)d_ws) > ws_size) return;  // insufficient workspace

  run_branch(x0, ei0, b0, w_c1, b_c1, w_c2, b_c2, fg0_w1, fg0_b1, fg0_w2, fg0_b2,
             fg0_g, fg0_bt, ff0_w1, ff0_b1, ff0_w2, ff0_b2, NNODES, 93, alpha, beta,
             xg0, AGG, H, POOL, CNT, CM, MU, VAR, SSQ, G1, Z1, stream);
  run_branch(x1, ei1, b1, w_c3, b_c3, w_c4, b_c4, fg1_w1, fg1_b1, fg1_w2, fg1_b2,
             fg1_g, fg1_bt, ff1_w1, ff1_b1, ff1_w2, ff1_b2, NNODES, 43, alpha1, beta1,
             xg1, AGG, H, POOL, CNT, CM, MU, VAR, SSQ, G1, Z1, stream);
}

// Round 2
// 2708.863 us; speedup vs baseline: 1.4754x; 1.4754x over previous
//
#include <hip/hip_runtime.h>
#include <hip/hip_bf16.h>
#include <math.h>

#define EDGES 800000
#define NNODES 100000
#define NGRAPH 1024
#define SCAN_B 256

typedef __attribute__((ext_vector_type(8))) short short8v;
typedef __attribute__((ext_vector_type(4))) float float4v;
typedef unsigned short ushort_t;

__device__ inline ushort_t f2bf(float f) {
  __hip_bfloat16 h = __float2bfloat16(f);
  return *reinterpret_cast<ushort_t*>(&h);
}
__device__ inline float bf2f(ushort_t u) {
  unsigned int x = ((unsigned int)u) << 16;
  return __uint_as_float(x);
}

// ---------------- CSR build ----------------
__global__ __launch_bounds__(256) void deg_k(const int* __restrict__ dst,
                                             int* __restrict__ deg, int E) {
  int e = blockIdx.x * 256 + threadIdx.x;
  if (e < E) atomicAdd(&deg[dst[e]], 1);
}

__global__ __launch_bounds__(SCAN_B) void scan_block_k(const int* __restrict__ deg,
                                                       int* __restrict__ scanned,
                                                       int* __restrict__ bsum, int n) {
  __shared__ int tmp[SCAN_B];
  int b = blockIdx.x, t = threadIdx.x, i = b * SCAN_B + t;
  int v = (i < n) ? deg[i] : 0;
  tmp[t] = v;
  __syncthreads();
  for (int off = 1; off < SCAN_B; off <<= 1) {
    int x = (t >= off) ? tmp[t - off] : 0;
    __syncthreads();
    tmp[t] += x;
    __syncthreads();
  }
  if (i < n) scanned[i] = tmp[t] - v;  // exclusive
  if (t == SCAN_B - 1) bsum[b] = tmp[t];
}

__global__ __launch_bounds__(512) void scan_sums_k(int* __restrict__ bsum, int nb) {
  __shared__ int tmp[512];
  int t = threadIdx.x;
  int v = (t < nb) ? bsum[t] : 0;
  tmp[t] = v;
  __syncthreads();
  for (int off = 1; off < 512; off <<= 1) {
    int x = (t >= off) ? tmp[t - off] : 0;
    __syncthreads();
    tmp[t] += x;
    __syncthreads();
  }
  if (t < nb) bsum[t] = tmp[t] - v;  // exclusive
}

__global__ __launch_bounds__(256) void scan_add_k(const int* __restrict__ scanned,
                                                  const int* __restrict__ bsum,
                                                  int* __restrict__ rowstart, int n,
                                                  int total) {
  int i = blockIdx.x * 256 + threadIdx.x;
  if (i < n) rowstart[i] = scanned[i] + bsum[i / SCAN_B];
  if (i == 0) rowstart[n] = total;
}

__global__ __launch_bounds__(256) void fill_k(const int* __restrict__ src,
                                              const int* __restrict__ dst,
                                              const int* __restrict__ rowstart,
                                              int* __restrict__ cur,
                                              int* __restrict__ adj, int E) {
  int e = blockIdx.x * 256 + threadIdx.x;
  if (e >= E) return;
  int d = dst[e];
  int p = rowstart[d] + atomicAdd(&cur[d], 1);
  adj[p] = src[e];
}

// ---------------- f32 -> padded bf16 ----------------
template <int KP>
__global__ __launch_bounds__(256) void tobf16_k(const float* __restrict__ x,
                                                ushort_t* __restrict__ out, int M,
                                                int F) {
  long i = (long)blockIdx.x * 256 + threadIdx.x;
  if (i >= (long)M * KP) return;
  int r = (int)(i / KP), c = (int)(i % KP);
  float v = (c < F) ? x[(long)r * F + c] : 0.f;
  out[i] = f2bf(v);
}

// ---------------- gather: out[i] = X[i] + sum_{j in nbr(i)} X[j]  (bf16) ----------------
template <int KP>
__global__ __launch_bounds__(256) void gather_k(const ushort_t* __restrict__ X,
                                                const int* __restrict__ rowstart,
                                                const int* __restrict__ adj,
                                                ushort_t* __restrict__ out, int M) {
  constexpr int CH = KP / 8;
  long tid = (long)blockIdx.x * 256 + threadIdx.x;
  if (tid >= (long)M * CH) return;
  int node = (int)(tid / CH), ch = (int)(tid % CH);
  int o = ch * 8;
  float acc[8];
  uint4 self = *(const uint4*)&X[(long)node * KP + o];
  {
    const unsigned int u[4] = {self.x, self.y, self.z, self.w};
#pragma unroll
    for (int i = 0; i < 4; ++i) {
      acc[2 * i] = __uint_as_float((u[i] & 0xFFFFu) << 16);
      acc[2 * i + 1] = __uint_as_float(u[i] & 0xFFFF0000u);
    }
  }
  int rs = rowstart[node], re = rowstart[node + 1];
  for (int e = rs; e < re; ++e) {
    int j = adj[e];
    uint4 v = *(const uint4*)&X[(long)j * KP + o];
    const unsigned int u[4] = {v.x, v.y, v.z, v.w};
#pragma unroll
    for (int i = 0; i < 4; ++i) {
      acc[2 * i] += __uint_as_float((u[i] & 0xFFFFu) << 16);
      acc[2 * i + 1] += __uint_as_float(u[i] & 0xFFFF0000u);
    }
  }
  uint4 r;
  unsigned int* p = &r.x;
#pragma unroll
  for (int i = 0; i < 4; ++i) {
    unsigned int lo = f2bf(acc[2 * i]);
    unsigned int hi = f2bf(acc[2 * i + 1]);
    p[i] = lo | (hi << 16);
  }
  *(uint4*)&out[(long)node * KP + o] = r;
}

// ---------------- weight transpose + bf16: WT[n][k] = W[k][n] ----------------
__global__ __launch_bounds__(256) void wt_k(const float* __restrict__ W,
                                            ushort_t* __restrict__ WT, int K, int N,
                                            int KP, int Npad) {
  int i = blockIdx.x * 256 + threadIdx.x;
  if (i >= Npad * KP) return;
  int n = i / KP, k = i % KP;
  float v = (k < K && n < N) ? W[(long)k * N + n] : 0.f;
  WT[i] = f2bf(v);
}

// ---------------- bf16 MFMA conv GEMM ----------------
// C = relu((A) @ W + bias); EPI 0: store bf16 [M][OW] (zero-pad cols >= Nc)
//                           EPI 2: fused segment mean/max pool (f32 atomics)
template <int KP, int EPI>
__global__ __launch_bounds__(256) void conv_gemm_k(
    const ushort_t* __restrict__ A, const ushort_t* __restrict__ WT,
    const float* __restrict__ bias, ushort_t* __restrict__ Cout, int M, int Nc,
    int OW, const int* __restrict__ bat, float* __restrict__ pool, int NCpool) {
  constexpr int LDSW = KP + 8;
  __shared__ ushort_t As[64][LDSW];
  __shared__ ushort_t Ws[64][LDSW];
  int tid = threadIdx.x;
  int row0 = blockIdx.y * 64, col0 = blockIdx.x * 64;
  constexpr int CH = KP / 8;
  constexpr int TOT = 64 * CH;
#pragma unroll
  for (int c = tid; c < TOT; c += 256) {
    int r = c / CH, s = c % CH;
    *(uint4*)&As[r][s * 8] = *(const uint4*)&A[(long)(row0 + r) * KP + s * 8];
  }
#pragma unroll
  for (int c = tid; c < TOT; c += 256) {
    int r = c / CH, s = c % CH;
    *(uint4*)&Ws[r][s * 8] = *(const uint4*)&WT[(long)(col0 + r) * KP + s * 8];
  }
  __syncthreads();

  int wid = tid >> 6, lane = tid & 63;
  int lr = lane & 15;
  int lk = (lane >> 4) * 8;
  float4v acc[4];
#pragma unroll
  for (int i = 0; i < 4; ++i) acc[i] = (float4v){0.f, 0.f, 0.f, 0.f};

#pragma unroll
  for (int ks = 0; ks < KP / 32; ++ks) {
    short8v a = *(const short8v*)&As[wid * 16 + lr][ks * 32 + lk];
#pragma unroll
    for (int nf = 0; nf < 4; ++nf) {
      short8v b = *(const short8v*)&Ws[nf * 16 + lr][ks * 32 + lk];
      acc[nf] = __builtin_amdgcn_mfma_f32_16x16x32_bf16(a, b, acc[nf], 0, 0, 0);
    }
  }

  if constexpr (EPI == 0) {
#pragma unroll
    for (int nf = 0; nf < 4; ++nf) {
      int gc = col0 + nf * 16 + lr;
      if (gc >= OW) continue;
      float bv = (gc < Nc) ? bias[gc] : 0.f;
#pragma unroll
      for (int i = 0; i < 4; ++i) {
        int gr = row0 + wid * 16 + ((lane >> 4) << 2) + i;
        if (gr < M) {
          float v = (gc < Nc) ? fmaxf(acc[nf][i] + bv, 0.f) : 0.f;
          Cout[(long)gr * OW + gc] = f2bf(v);
        }
      }
    }
  } else {
    __shared__ float Ct[64][68];
    __shared__ int gid[64];
    if (tid < 64) gid[tid] = (row0 + tid < M) ? bat[row0 + tid] : -1;
#pragma unroll
    for (int nf = 0; nf < 4; ++nf) {
      int c = nf * 16 + lr;
      int gc = col0 + c;
      float bv = (gc < Nc) ? bias[gc] : 0.f;
#pragma unroll
      for (int i = 0; i < 4; ++i) {
        int r = wid * 16 + ((lane >> 4) << 2) + i;
        float v = (gc < Nc) ? fmaxf(acc[nf][i] + bv, 0.f) : 0.f;
        Ct[r][c] = v;
      }
    }
    __syncthreads();
    int c = tid & 63, grp = tid >> 6;
    int gc = col0 + c;
    if (gc < Nc) {
      float s = 0.f, mx = 0.f;
      int curg = -1;
      bool has = false;
      for (int r = grp * 16; r < grp * 16 + 16; ++r) {
        int g = gid[r];
        if (g != curg) {
          if (has) {
            atomicAdd(&pool[(long)curg * 2 * NCpool + gc], s);
            atomicMax((unsigned int*)&pool[(long)curg * 2 * NCpool + NCpool + gc],
                      __float_as_uint(mx));
          }
          curg = g;
          s = 0.f;
          mx = 0.f;
          has = (g >= 0);
        }
        if (g >= 0) {
          float v = Ct[r][c];
          s += v;
          mx = fmaxf(mx, v);
        }
      }
      if (has) {
        atomicAdd(&pool[(long)curg * 2 * NCpool + gc], s);
        atomicMax((unsigned int*)&pool[(long)curg * 2 * NCpool + NCpool + gc],
                  __float_as_uint(mx));
      }
    }
  }
}

// ---------------- f32 tiled GEMM for FC layers ----------------
// EPI: 0 = relu + store, 1 = store
template <int EPI>
__global__ __launch_bounds__(256) void gemm_k(const float* __restrict__ A0,
                                              const float* __restrict__ W,
                                              const float* __restrict__ bias,
                                              float* __restrict__ C, int M, int K,
                                              int Nc, int ldc) {
  __shared__ __align__(16) float As[16][68];
  __shared__ __align__(16) float Bs[16][68];
  int tid = threadIdx.x;
  int tx = tid & 15, ty = tid >> 4;
  int row0 = blockIdx.y * 64, col0 = blockIdx.x * 64;
  float acc[4][4] = {};

  for (int k0 = 0; k0 < K; k0 += 16) {
#pragma unroll
    for (int i = 0; i < 4; ++i) {
      int e = tid + 256 * i;
      int r = e >> 4, k = e & 15;
      int gr = row0 + r, gk = k0 + k;
      As[k][r] = (gr < M && gk < K) ? A0[(long)gr * K + gk] : 0.f;
    }
#pragma unroll
    for (int i = 0; i < 4; ++i) {
      int e = tid + 256 * i;
      int k = e >> 6, c = e & 63;
      int gk = k0 + k, gc = col0 + c;
      Bs[k][c] = (gk < K && gc < Nc) ? W[(long)gk * Nc + gc] : 0.f;
    }
    __syncthreads();
#pragma unroll
    for (int k = 0; k < 16; ++k) {
      float4 a = *reinterpret_cast<const float4*>(&As[k][ty * 4]);
      float4 b = *reinterpret_cast<const float4*>(&Bs[k][tx * 4]);
      float av[4] = {a.x, a.y, a.z, a.w};
      float bv[4] = {b.x, b.y, b.z, b.w};
#pragma unroll
      for (int i = 0; i < 4; ++i)
#pragma unroll
        for (int j = 0; j < 4; ++j) acc[i][j] += av[i] * bv[j];
    }
    __syncthreads();
  }
#pragma unroll
  for (int i = 0; i < 4; ++i) {
    int gr = row0 + ty * 4 + i;
    if (gr >= M) continue;
#pragma unroll
    for (int j = 0; j < 4; ++j) {
      int gc = col0 + tx * 4 + j;
      if (gc >= Nc) continue;
      float v = acc[i][j] + bias[gc];
      if (EPI == 0) v = fmaxf(v, 0.f);
      C[(long)gr * ldc + gc] = v;
    }
  }
}

// ---------------- small helpers ----------------
__global__ void count_k(const int* __restrict__ bat, float* __restrict__ cnt, int n) {
  int i = blockIdx.x * 256 + threadIdx.x;
  if (i < n) atomicAdd(&cnt[bat[i]], 1.f);
}

__global__ void mean_fin_k(float* __restrict__ pool, const float* __restrict__ cnt,
                           int Bn, int NC) {
  int idx = blockIdx.x * 256 + threadIdx.x;
  if (idx >= Bn * NC) return;
  int g = idx / NC, c = idx % NC;
  pool[(long)g * 2 * NC + c] /= fmaxf(cnt[g], 1.f);
}

__global__ void colmean_k(const float* __restrict__ X, float* __restrict__ cm,
                          int Rows, int Cols) {
  int j = blockIdx.x * 256 + threadIdx.x;
  if (j >= Cols) return;
  float s = 0.f;
  for (int r = 0; r < Rows; ++r) s += X[(long)r * Cols + j];
  cm[j] = s / Rows;
}

__global__ void ssq_k(const float* __restrict__ X, const float* __restrict__ cm,
                      float* __restrict__ ssq, int Rows, int Cols) {
  long total = (long)Rows * Cols;
  long stride = (long)gridDim.x * 256;
  float s = 0.f;
  for (long idx = (long)blockIdx.x * 256 + threadIdx.x; idx < total; idx += stride) {
    int c = (int)(idx % Cols);
    float d = X[idx] - cm[c];
    s += d * d;
  }
  for (int off = 32; off > 0; off >>= 1) s += __shfl_down(s, off);
  if ((threadIdx.x & 63) == 0) atomicAdd(ssq, s);
}

__global__ void pn_apply_k(float* __restrict__ X, const float* __restrict__ cm,
                           const float* __restrict__ ssq, int Rows, int Cols) {
  long idx = (long)blockIdx.x * 256 + threadIdx.x;
  if (idx >= (long)Rows * Cols) return;
  int c = (int)(idx % Cols);
  float scale = 1.f / sqrtf(1e-5f + ssq[0] / Rows);
  X[idx] = (X[idx] - cm[c]) * scale;
}

__global__ void bn_stats_k(const float* __restrict__ X, float* __restrict__ mu,
                           float* __restrict__ var, int Rows, int Cols) {
  int j = blockIdx.x * blockDim.x + threadIdx.x;
  if (j >= Cols) return;
  float s = 0.f, s2 = 0.f;
  for (int r = 0; r < Rows; ++r) {
    float v = X[(long)r * Cols + j];
    s += v;
    s2 += v * v;
  }
  float m = s / Rows;
  mu[j] = m;
  var[j] = s2 / Rows - m * m;
}

__global__ void bn_apply_k(float* __restrict__ X, const float* __restrict__ mu,
                           const float* __restrict__ var, const float* __restrict__ g,
                           const float* __restrict__ b, int Rows, int Cols) {
  long idx = (long)blockIdx.x * 256 + threadIdx.x;
  if (idx >= (long)Rows * Cols) return;
  int c = (int)(idx % Cols);
  X[idx] = (X[idx] - mu[c]) / sqrtf(var[c] + 1e-5f) * g[c] + b[c];
}

__global__ __launch_bounds__(64) void ff2_k(const float* __restrict__ Z,
                                            const float* __restrict__ W2,
                                            const float* __restrict__ b2,
                                            float* __restrict__ alpha,
                                            float* __restrict__ beta, int K) {
  int row = blockIdx.x;
  int t = threadIdx.x;
  float s0 = 0.f, s1 = 0.f;
  for (int k = t; k < K; k += 64) {
    float z = Z[(long)row * K + k];
    s0 += z * W2[2 * k];
    s1 += z * W2[2 * k + 1];
  }
  for (int off = 32; off > 0; off >>= 1) {
    s0 += __shfl_down(s0, off);
    s1 += __shfl_down(s1, off);
  }
  if (t == 0) {
    alpha[row] = 1.f / (1.f + expf(-(s0 + b2[0])));
    beta[row] = 1.f / (1.f + expf(-(s1 + b2[1])));
  }
}

// ---------------- branch driver ----------------
template <int KP>
static void run_branch(const float* x, const int* ei, const int* bat,
                       const float* wc1, const float* bc1, const float* wc2,
                       const float* bc2, const float* fgw1, const float* fgb1,
                       const float* fgw2, const float* fgb2, const float* fgg,
                       const float* fgbt, const float* ffw1, const float* ffb1,
                       const float* ffw2, const float* ffb2, int N, int F,
                       float* out_alpha, float* out_beta, float* out_xg,
                       ushort_t* XB, ushort_t* XA, ushort_t* H, ushort_t* WT,
                       int* deg, int* scanned, int* rowstart, int* cur, int* bsum,
                       int* adj, float* POOL, float* CNT, float* CM, float* MU,
                       float* VAR, float* SSQ, float* G1, float* Z1,
                       hipStream_t stream) {
  const int NC = F * 10;
  const int Bn = NGRAPH;
  const int* src = ei;
  const int* dst = ei + EDGES;
  const int MB = (N + 63) / 64;
  const int nb = (N + SCAN_B - 1) / SCAN_B;

  // CSR build
  hipMemsetAsync(deg, 0, (size_t)N * 4, stream);
  hipMemsetAsync(cur, 0, (size_t)N * 4, stream);
  deg_k<<<(EDGES + 255) / 256, 256, 0, stream>>>(dst, deg, EDGES);
  scan_block_k<<<nb, SCAN_B, 0, stream>>>(deg, scanned, bsum, N);
  scan_sums_k<<<1, 512, 0, stream>>>(bsum, nb);
  scan_add_k<<<nb, 256, 0, stream>>>(scanned, bsum, rowstart, N, EDGES);
  fill_k<<<(EDGES + 255) / 256, 256, 0, stream>>>(src, dst, rowstart, cur, adj, EDGES);

  constexpr int CH = KP / 8;
  // x -> bf16 padded
  tobf16_k<KP><<<(int)(((long)N * KP + 255) / 256), 256, 0, stream>>>(x, XB, N, F);
  // conv1
  gather_k<KP><<<(int)(((long)N * CH + 255) / 256), 256, 0, stream>>>(XB, rowstart, adj, XA, N);
  wt_k<<<(((F + 63) / 64) * 64 * KP + 255) / 256, 256, 0, stream>>>(wc1, WT, F, F, KP, ((F + 63) / 64) * 64);
  dim3 g1((F + 63) / 64, MB);
  conv_gemm_k<KP, 0><<<g1, 256, 0, stream>>>(XA, WT, bc1, H, N, F, KP, nullptr, nullptr, 0);
  // conv2 + fused pool
  gather_k<KP><<<(int)(((long)N * CH + 255) / 256), 256, 0, stream>>>(H, rowstart, adj, XA, N);
  int Npad2 = ((NC + 63) / 64) * 64;
  wt_k<<<(Npad2 * KP + 255) / 256, 256, 0, stream>>>(wc2, WT, F, NC, KP, Npad2);
  hipMemsetAsync(POOL, 0, (size_t)Bn * 2 * NC * 4, stream);
  hipMemsetAsync(CNT, 0, Bn * 4, stream);
  dim3 g2(Npad2 / 64, MB);
  conv_gemm_k<KP, 2><<<g2, 256, 0, stream>>>(XA, WT, bc2, nullptr, N, NC, 0, bat, POOL, NC);
  count_k<<<(N + 255) / 256, 256, 0, stream>>>(bat, CNT, N);
  mean_fin_k<<<(Bn * NC + 255) / 256, 256, 0, stream>>>(POOL, CNT, Bn, NC);

  // pairnorm on [Bn, 2*NC]
  int Cols = 2 * NC;
  colmean_k<<<(Cols + 255) / 256, 256, 0, stream>>>(POOL, CM, Bn, Cols);
  hipMemsetAsync(SSQ, 0, 4, stream);
  ssq_k<<<512, 256, 0, stream>>>(POOL, CM, SSQ, Bn, Cols);
  pn_apply_k<<<(int)(((long)Bn * Cols + 255) / 256), 256, 0, stream>>>(POOL, CM, SSQ, Bn, Cols);

  // FC1 relu (f32)
  dim3 gf1(1024 / 64, Bn / 64);
  gemm_k<0><<<gf1, 256, 0, stream>>>(POOL, fgw1, fgb1, G1, Bn, Cols, 1024, 1024);
  // FC2 (no act) -> xg
  dim3 gf2(512 / 64, Bn / 64);
  gemm_k<1><<<gf2, 256, 0, stream>>>(G1, fgw2, fgb2, out_xg, Bn, 1024, 512, 512);
  // batchnorm in place
  bn_stats_k<<<2, 256, 0, stream>>>(out_xg, MU, VAR, Bn, 512);
  bn_apply_k<<<(Bn * 512 + 255) / 256, 256, 0, stream>>>(out_xg, MU, VAR, fgg, fgbt, Bn, 512);
  // FF1 relu
  dim3 gff(256 / 64, Bn / 64);
  gemm_k<0><<<gff, 256, 0, stream>>>(out_xg, ffw1, ffb1, Z1, Bn, 512, 256, 256);
  // FF2 + sigmoid
  ff2_k<<<Bn, 64, 0, stream>>>(Z1, ffw2, ffb2, out_alpha, out_beta, 256);
}

extern "C" void kernel_launch(void* const* d_in, const int* in_sizes, int n_in,
                              void* d_out, int out_size, void* d_ws, size_t ws_size,
                              hipStream_t stream) {
  if (n_in < 34) return;
  const float* x0 = (const float*)d_in[0];
  const int* ei0 = (const int*)d_in[1];
  const int* b0 = (const int*)d_in[2];
  const float* x1 = (const float*)d_in[3];
  const int* ei1 = (const int*)d_in[4];
  const int* b1 = (const int*)d_in[5];
  const float* w_c1 = (const float*)d_in[6];
  const float* b_c1 = (const float*)d_in[7];
  const float* w_c2 = (const float*)d_in[8];
  const float* b_c2 = (const float*)d_in[9];
  const float* w_c3 = (const float*)d_in[10];
  const float* b_c3 = (const float*)d_in[11];
  const float* w_c4 = (const float*)d_in[12];
  const float* b_c4 = (const float*)d_in[13];
  const float* fg0_w1 = (const float*)d_in[14];
  const float* fg0_b1 = (const float*)d_in[15];
  const float* fg0_w2 = (const float*)d_in[16];
  const float* fg0_b2 = (const float*)d_in[17];
  const float* fg0_g = (const float*)d_in[18];
  const float* fg0_bt = (const float*)d_in[19];
  const float* fg1_w1 = (const float*)d_in[20];
  const float* fg1_b1 = (const float*)d_in[21];
  const float* fg1_w2 = (const float*)d_in[22];
  const float* fg1_b2 = (const float*)d_in[23];
  const float* fg1_g = (const float*)d_in[24];
  const float* fg1_bt = (const float*)d_in[25];
  const float* ff0_w1 = (const float*)d_in[26];
  const float* ff0_b1 = (const float*)d_in[27];
  const float* ff0_w2 = (const float*)d_in[28];
  const float* ff0_b2 = (const float*)d_in[29];
  const float* ff1_w1 = (const float*)d_in[30];
  const float* ff1_b1 = (const float*)d_in[31];
  const float* ff1_w2 = (const float*)d_in[32];
  const float* ff1_b2 = (const float*)d_in[33];

  float* out = (float*)d_out;
  float* alpha = out;
  float* beta = out + 1024;
  float* xg0 = out + 2048;
  float* xg1 = out + 2048 + 1024 * 512;
  float* alpha1 = out + 2048 + 2 * 1024 * 512;
  float* beta1 = alpha1 + 1024;

  char* w = (char*)d_ws;
  auto alloc = [&](size_t bytes) -> void* {
    void* p = (void*)w;
    w += ((bytes + 255) / 256) * 256;
    return p;
  };
  const int Mpad = ((NNODES + 63) / 64) * 64;
  ushort_t* XB = (ushort_t*)alloc((size_t)Mpad * 96 * 2);
  ushort_t* XA = (ushort_t*)alloc((size_t)Mpad * 96 * 2);
  ushort_t* H = (ushort_t*)alloc((size_t)Mpad * 96 * 2);
  ushort_t* WT = (ushort_t*)alloc((size_t)960 * 96 * 2);
  int* deg = (int*)alloc((size_t)(NNODES + 1) * 4);
  int* scanned = (int*)alloc((size_t)(NNODES + 1) * 4);
  int* rowstart = (int*)alloc((size_t)(NNODES + 1) * 4);
  int* cur = (int*)alloc((size_t)NNODES * 4);
  int* bsum = (int*)alloc(512 * 4);
  int* adj = (int*)alloc((size_t)EDGES * 4);
  float* POOL = (float*)alloc((size_t)NGRAPH * 1860 * 4);
  float* CNT = (float*)alloc(NGRAPH * 4);
  float* CM = (float*)alloc(1860 * 4);
  float* MU = (float*)alloc(512 * 4);
  float* VAR = (float*)alloc(512 * 4);
  float* SSQ = (float*)alloc(256);
  float* G1 = (float*)alloc((size_t)NGRAPH * 1024 * 4);
  float* Z1 = (float*)alloc((size_t)NGRAPH * 256 * 4);
  if ((size_t)(w - (char*)d_ws) > ws_size) return;

  run_branch<96>(x0, ei0, b0, w_c1, b_c1, w_c2, b_c2, fg0_w1, fg0_b1, fg0_w2, fg0_b2,
                 fg0_g, fg0_bt, ff0_w1, ff0_b1, ff0_w2, ff0_b2, NNODES, 93, alpha,
                 beta, xg0, XB, XA, H, WT, deg, scanned, rowstart, cur, bsum, adj,
                 POOL, CNT, CM, MU, VAR, SSQ, G1, Z1, stream);
  run_branch<64>(x1, ei1, b1, w_c3, b_c3, w_c4, b_c4, fg1_w1, fg1_b1, fg1_w2, fg1_b2,
                 fg1_g, fg1_bt, ff1_w1, ff1_b1, ff1_w2, ff1_b2, NNODES, 43, alpha1,
                 beta1, xg1, XB, XA, H, WT, deg, scanned, rowstart, cur, bsum, adj,
                 POOL, CNT, CM, MU, VAR, SSQ, G1, Z1, stream);
}

// Round 3
// 1306.376 us; speedup vs baseline: 3.0594x; 2.0736x over previous
//
#include <hip/hip_runtime.h>
#include <hip/hip_bf16.h>
#include <math.h>

#define EDGES 800000
#define NNODES 100000
#define NGRAPH 1024
#define SCAN_B 256

typedef __attribute__((ext_vector_type(8))) short short8v;
typedef __attribute__((ext_vector_type(4))) float float4v;
typedef unsigned short ushort_t;

__device__ inline ushort_t f2bf(float f) {
  __hip_bfloat16 h = __float2bfloat16(f);
  return *reinterpret_cast<ushort_t*>(&h);
}

// ---------------- CSR build ----------------
__global__ __launch_bounds__(256) void deg_k(const int* __restrict__ dst,
                                             int* __restrict__ deg, int E) {
  int e = blockIdx.x * 256 + threadIdx.x;
  if (e < E) atomicAdd(&deg[dst[e]], 1);
}

__global__ __launch_bounds__(SCAN_B) void scan_block_k(const int* __restrict__ deg,
                                                       int* __restrict__ scanned,
                                                       int* __restrict__ bsum, int n) {
  __shared__ int tmp[SCAN_B];
  int b = blockIdx.x, t = threadIdx.x, i = b * SCAN_B + t;
  int v = (i < n) ? deg[i] : 0;
  tmp[t] = v;
  __syncthreads();
  for (int off = 1; off < SCAN_B; off <<= 1) {
    int x = (t >= off) ? tmp[t - off] : 0;
    __syncthreads();
    tmp[t] += x;
    __syncthreads();
  }
  if (i < n) scanned[i] = tmp[t] - v;  // exclusive
  if (t == SCAN_B - 1) bsum[b] = tmp[t];
}

__global__ __launch_bounds__(512) void scan_sums_k(int* __restrict__ bsum, int nb) {
  __shared__ int tmp[512];
  int t = threadIdx.x;
  int v = (t < nb) ? bsum[t] : 0;
  tmp[t] = v;
  __syncthreads();
  for (int off = 1; off < 512; off <<= 1) {
    int x = (t >= off) ? tmp[t - off] : 0;
    __syncthreads();
    tmp[t] += x;
    __syncthreads();
  }
  if (t < nb) bsum[t] = tmp[t] - v;  // exclusive
}

__global__ __launch_bounds__(256) void scan_add_k(const int* __restrict__ scanned,
                                                  const int* __restrict__ bsum,
                                                  int* __restrict__ rowstart, int n,
                                                  int total) {
  int i = blockIdx.x * 256 + threadIdx.x;
  if (i < n) rowstart[i] = scanned[i] + bsum[i / SCAN_B];
  if (i == 0) rowstart[n] = total;
}

__global__ __launch_bounds__(256) void fill_k(const int* __restrict__ src,
                                              const int* __restrict__ dst,
                                              const int* __restrict__ rowstart,
                                              int* __restrict__ cur,
                                              int* __restrict__ adj, int E) {
  int e = blockIdx.x * 256 + threadIdx.x;
  if (e >= E) return;
  int d = dst[e];
  int p = rowstart[d] + atomicAdd(&cur[d], 1);
  adj[p] = src[e];
}

// ---------------- f32 -> padded bf16 ----------------
template <int KP>
__global__ __launch_bounds__(256) void tobf16_k(const float* __restrict__ x,
                                                ushort_t* __restrict__ out, int M,
                                                int F) {
  long i = (long)blockIdx.x * 256 + threadIdx.x;
  if (i >= (long)M * KP) return;
  int r = (int)(i / KP), c = (int)(i % KP);
  float v = (c < F) ? x[(long)r * F + c] : 0.f;
  out[i] = f2bf(v);
}

// ---------------- gather: out[i] = X[i] + sum_{j in nbr(i)} X[j]  (bf16) ----------------
template <int KP>
__global__ __launch_bounds__(256) void gather_k(const ushort_t* __restrict__ X,
                                                const int* __restrict__ rowstart,
                                                const int* __restrict__ adj,
                                                ushort_t* __restrict__ out, int M) {
  constexpr int CH = KP / 8;
  long tid = (long)blockIdx.x * 256 + threadIdx.x;
  if (tid >= (long)M * CH) return;
  int node = (int)(tid / CH), ch = (int)(tid % CH);
  int o = ch * 8;
  float acc[8];
  uint4 self = *(const uint4*)&X[(long)node * KP + o];
  {
    const unsigned int u[4] = {self.x, self.y, self.z, self.w};
#pragma unroll
    for (int i = 0; i < 4; ++i) {
      acc[2 * i] = __uint_as_float((u[i] & 0xFFFFu) << 16);
      acc[2 * i + 1] = __uint_as_float(u[i] & 0xFFFF0000u);
    }
  }
  int rs = rowstart[node], re = rowstart[node + 1];
  for (int e = rs; e < re; ++e) {
    int j = adj[e];
    uint4 v = *(const uint4*)&X[(long)j * KP + o];
    const unsigned int u[4] = {v.x, v.y, v.z, v.w};
#pragma unroll
    for (int i = 0; i < 4; ++i) {
      acc[2 * i] += __uint_as_float((u[i] & 0xFFFFu) << 16);
      acc[2 * i + 1] += __uint_as_float(u[i] & 0xFFFF0000u);
    }
  }
  uint4 r;
  unsigned int* p = &r.x;
#pragma unroll
  for (int i = 0; i < 4; ++i) {
    unsigned int lo = f2bf(acc[2 * i]);
    unsigned int hi = f2bf(acc[2 * i + 1]);
    p[i] = lo | (hi << 16);
  }
  *(uint4*)&out[(long)node * KP + o] = r;
}

// ---------------- weight transpose + bf16: WT[n][k] = W[k][n] ----------------
__global__ __launch_bounds__(256) void wt_k(const float* __restrict__ W,
                                            ushort_t* __restrict__ WT, int K, int N,
                                            int KP, int Npad) {
  int i = blockIdx.x * 256 + threadIdx.x;
  if (i >= Npad * KP) return;
  int n = i / KP, k = i % KP;
  float v = (k < K && n < N) ? W[(long)k * N + n] : 0.f;
  WT[i] = f2bf(v);
}

// ---------------- bf16 MFMA conv GEMM ----------------
template <int KP, int EPI>
__global__ __launch_bounds__(256) void conv_gemm_k(
    const ushort_t* __restrict__ A, const ushort_t* __restrict__ WT,
    const float* __restrict__ bias, ushort_t* __restrict__ Cout, int M, int Nc,
    int OW, const int* __restrict__ bat, float* __restrict__ pool, int NCpool) {
  constexpr int LDSW = KP + 8;
  __shared__ ushort_t As[64][LDSW];
  __shared__ ushort_t Ws[64][LDSW];
  int tid = threadIdx.x;
  int row0 = blockIdx.y * 64, col0 = blockIdx.x * 64;
  constexpr int CH = KP / 8;
  constexpr int TOT = 64 * CH;
#pragma unroll
  for (int c = tid; c < TOT; c += 256) {
    int r = c / CH, s = c % CH;
    *(uint4*)&As[r][s * 8] = *(const uint4*)&A[(long)(row0 + r) * KP + s * 8];
  }
#pragma unroll
  for (int c = tid; c < TOT; c += 256) {
    int r = c / CH, s = c % CH;
    *(uint4*)&Ws[r][s * 8] = *(const uint4*)&WT[(long)(col0 + r) * KP + s * 8];
  }
  __syncthreads();

  int wid = tid >> 6, lane = tid & 63;
  int lr = lane & 15;
  int lk = (lane >> 4) * 8;
  float4v acc[4];
#pragma unroll
  for (int i = 0; i < 4; ++i) acc[i] = (float4v){0.f, 0.f, 0.f, 0.f};

#pragma unroll
  for (int ks = 0; ks < KP / 32; ++ks) {
    short8v a = *(const short8v*)&As[wid * 16 + lr][ks * 32 + lk];
#pragma unroll
    for (int nf = 0; nf < 4; ++nf) {
      short8v b = *(const short8v*)&Ws[nf * 16 + lr][ks * 32 + lk];
      acc[nf] = __builtin_amdgcn_mfma_f32_16x16x32_bf16(a, b, acc[nf], 0, 0, 0);
    }
  }

  if constexpr (EPI == 0) {
#pragma unroll
    for (int nf = 0; nf < 4; ++nf) {
      int gc = col0 + nf * 16 + lr;
      if (gc >= OW) continue;
      float bv = (gc < Nc) ? bias[gc] : 0.f;
#pragma unroll
      for (int i = 0; i < 4; ++i) {
        int gr = row0 + wid * 16 + ((lane >> 4) << 2) + i;
        if (gr < M) {
          float v = (gc < Nc) ? fmaxf(acc[nf][i] + bv, 0.f) : 0.f;
          Cout[(long)gr * OW + gc] = f2bf(v);
        }
      }
    }
  } else {
    __shared__ float Ct[64][68];
    __shared__ int gid[64];
    if (tid < 64) gid[tid] = (row0 + tid < M) ? bat[row0 + tid] : -1;
#pragma unroll
    for (int nf = 0; nf < 4; ++nf) {
      int c = nf * 16 + lr;
      int gc = col0 + c;
      float bv = (gc < Nc) ? bias[gc] : 0.f;
#pragma unroll
      for (int i = 0; i < 4; ++i) {
        int r = wid * 16 + ((lane >> 4) << 2) + i;
        float v = (gc < Nc) ? fmaxf(acc[nf][i] + bv, 0.f) : 0.f;
        Ct[r][c] = v;
      }
    }
    __syncthreads();
    int c = tid & 63, grp = tid >> 6;
    int gc = col0 + c;
    if (gc < Nc) {
      float s = 0.f, mx = 0.f;
      int curg = -1;
      bool has = false;
      for (int r = grp * 16; r < grp * 16 + 16; ++r) {
        int g = gid[r];
        if (g != curg) {
          if (has) {
            atomicAdd(&pool[(long)curg * 2 * NCpool + gc], s);
            atomicMax((unsigned int*)&pool[(long)curg * 2 * NCpool + NCpool + gc],
                      __float_as_uint(mx));
          }
          curg = g;
          s = 0.f;
          mx = 0.f;
          has = (g >= 0);
        }
        if (g >= 0) {
          float v = Ct[r][c];
          s += v;
          mx = fmaxf(mx, v);
        }
      }
      if (has) {
        atomicAdd(&pool[(long)curg * 2 * NCpool + gc], s);
        atomicMax((unsigned int*)&pool[(long)curg * 2 * NCpool + NCpool + gc],
                  __float_as_uint(mx));
      }
    }
  }
}

// ---------------- split-K f32 GEMM for FC layers ----------------
__global__ __launch_bounds__(256) void gemm_sk_k(const float* __restrict__ A,
                                                 const float* __restrict__ W,
                                                 float* __restrict__ PART, int M,
                                                 int K, int Nc, int Kc) {
  __shared__ __align__(16) float As[16][68];
  __shared__ __align__(16) float Bs[16][68];
  int tid = threadIdx.x;
  int tx = tid & 15, ty = tid >> 4;
  int row0 = blockIdx.y * 64, col0 = blockIdx.x * 64;
  int kbeg = blockIdx.z * Kc;
  int kend = min(K, kbeg + Kc);
  float acc[4][4] = {};

  for (int k0 = kbeg; k0 < kend; k0 += 16) {
#pragma unroll
    for (int i = 0; i < 4; ++i) {
      int e = tid + 256 * i;
      int r = e >> 4, k = e & 15;
      int gr = row0 + r, gk = k0 + k;
      As[k][r] = (gr < M && gk < kend) ? A[(long)gr * K + gk] : 0.f;
    }
#pragma unroll
    for (int i = 0; i < 4; ++i) {
      int e = tid + 256 * i;
      int k = e >> 6, c = e & 63;
      int gk = k0 + k, gc = col0 + c;
      Bs[k][c] = (gk < kend && gc < Nc) ? W[(long)gk * Nc + gc] : 0.f;
    }
    __syncthreads();
#pragma unroll
    for (int k = 0; k < 16; ++k) {
      float4 a = *reinterpret_cast<const float4*>(&As[k][ty * 4]);
      float4 b = *reinterpret_cast<const float4*>(&Bs[k][tx * 4]);
      float av[4] = {a.x, a.y, a.z, a.w};
      float bv[4] = {b.x, b.y, b.z, b.w};
#pragma unroll
      for (int i = 0; i < 4; ++i)
#pragma unroll
        for (int j = 0; j < 4; ++j) acc[i][j] += av[i] * bv[j];
    }
    __syncthreads();
  }
  float* P = PART + (long)blockIdx.z * M * Nc;
#pragma unroll
  for (int i = 0; i < 4; ++i) {
    int gr = row0 + ty * 4 + i;
    if (gr >= M) continue;
#pragma unroll
    for (int j = 0; j < 4; ++j) {
      int gc = col0 + tx * 4 + j;
      if (gc < Nc) P[(long)gr * Nc + gc] = acc[i][j];
    }
  }
}

__global__ __launch_bounds__(256) void sk_epi_k(const float* __restrict__ PART,
                                                const float* __restrict__ bias,
                                                float* __restrict__ C, int M, int Nc,
                                                int SK, int ldc, int relu) {
  long idx = (long)blockIdx.x * 256 + threadIdx.x;
  if (idx >= (long)M * Nc) return;
  int r = (int)(idx / Nc), c = (int)(idx % Nc);
  float s = bias[c];
  for (int z = 0; z < SK; ++z) s += PART[(long)z * M * Nc + idx];
  if (relu) s = fmaxf(s, 0.f);
  C[(long)r * ldc + c] = s;
}

// ---------------- pool helpers ----------------
__global__ void count_k(const int* __restrict__ bat, float* __restrict__ cnt, int n) {
  int i = blockIdx.x * 256 + threadIdx.x;
  if (i < n) atomicAdd(&cnt[bat[i]], 1.f);
}

__global__ void mean_fin_k(float* __restrict__ pool, const float* __restrict__ cnt,
                           int Bn, int NC) {
  int idx = blockIdx.x * 256 + threadIdx.x;
  if (idx >= Bn * NC) return;
  int g = idx / NC, c = idx % NC;
  pool[(long)g * 2 * NC + c] /= fmaxf(cnt[g], 1.f);
}

// ---------------- pairnorm (fused stats: colmean + total ssq via E[x^2]) ----------------
__global__ __launch_bounds__(256) void colstat_k(const float* __restrict__ X,
                                                 float* __restrict__ cm,
                                                 float* __restrict__ ssqtot, int Rows,
                                                 int Cols) {
  __shared__ float sred[256];
  int c0 = blockIdx.x * 64;
  int t = threadIdx.x;
  int c = c0 + (t & 63);
  int rg = t >> 6;
  float s = 0.f, s2 = 0.f;
  if (c < Cols) {
    for (int r = rg; r < Rows; r += 4) {
      float v = X[(long)r * Cols + c];
      s += v;
      s2 += v * v;
    }
  }
  sred[t] = s;
  __syncthreads();
  if (t < 64) {
    float tot = sred[t] + sred[t + 64] + sred[t + 128] + sred[t + 192];
    if (c0 + t < Cols) cm[c0 + t] = tot / Rows;
  }
  for (int off = 32; off > 0; off >>= 1) s2 += __shfl_down(s2, off);
  if ((t & 63) == 0) atomicAdd(ssqtot, s2);
}

__global__ __launch_bounds__(256) void pn_scale_k(const float* __restrict__ cm,
                                                  const float* __restrict__ ssqtot,
                                                  float* __restrict__ scale, int Rows,
                                                  int Cols) {
  __shared__ float red[256];
  int t = threadIdx.x;
  float s = 0.f;
  for (int i = t; i < Cols; i += 256) {
    float v = cm[i];
    s += v * v;
  }
  red[t] = s;
  __syncthreads();
  for (int off = 128; off > 0; off >>= 1) {
    if (t < off) red[t] += red[t + off];
    __syncthreads();
  }
  if (t == 0) {
    float ssq = ssqtot[0] - (float)Rows * red[0];
    scale[0] = 1.f / sqrtf(1e-5f + ssq / Rows);
  }
}

__global__ void pn_apply_k(float* __restrict__ X, const float* __restrict__ cm,
                           const float* __restrict__ scale, int Rows, int Cols) {
  long idx = (long)blockIdx.x * 256 + threadIdx.x;
  if (idx >= (long)Rows * Cols) return;
  int c = (int)(idx % Cols);
  X[idx] = (X[idx] - cm[c]) * scale[0];
}

// ---------------- batchnorm ----------------
__global__ __launch_bounds__(256) void bn_stats2_k(const float* __restrict__ X,
                                                   float* __restrict__ mu,
                                                   float* __restrict__ var, int Rows,
                                                   int Cols) {
  __shared__ float s1[256], s2[256];
  int c0 = blockIdx.x * 64;
  int t = threadIdx.x;
  int c = c0 + (t & 63);
  int rg = t >> 6;
  float a = 0.f, b = 0.f;
  if (c < Cols) {
    for (int r = rg; r < Rows; r += 4) {
      float v = X[(long)r * Cols + c];
      a += v;
      b += v * v;
    }
  }
  s1[t] = a;
  s2[t] = b;
  __syncthreads();
  if (t < 64 && c0 + t < Cols) {
    float m = (s1[t] + s1[t + 64] + s1[t + 128] + s1[t + 192]) / Rows;
    float q = (s2[t] + s2[t + 64] + s2[t + 128] + s2[t + 192]) / Rows - m * m;
    mu[c0 + t] = m;
    var[c0 + t] = q;
  }
}

__global__ void bn_apply_k(float* __restrict__ X, const float* __restrict__ mu,
                           const float* __restrict__ var, const float* __restrict__ g,
                           const float* __restrict__ b, int Rows, int Cols) {
  long idx = (long)blockIdx.x * 256 + threadIdx.x;
  if (idx >= (long)Rows * Cols) return;
  int c = (int)(idx % Cols);
  X[idx] = (X[idx] - mu[c]) / sqrtf(var[c] + 1e-5f) * g[c] + b[c];
}

__global__ __launch_bounds__(64) void ff2_k(const float* __restrict__ Z,
                                            const float* __restrict__ W2,
                                            const float* __restrict__ b2,
                                            float* __restrict__ alpha,
                                            float* __restrict__ beta, int K) {
  int row = blockIdx.x;
  int t = threadIdx.x;
  float s0 = 0.f, s1 = 0.f;
  for (int k = t; k < K; k += 64) {
    float z = Z[(long)row * K + k];
    s0 += z * W2[2 * k];
    s1 += z * W2[2 * k + 1];
  }
  for (int off = 32; off > 0; off >>= 1) {
    s0 += __shfl_down(s0, off);
    s1 += __shfl_down(s1, off);
  }
  if (t == 0) {
    alpha[row] = 1.f / (1.f + expf(-(s0 + b2[0])));
    beta[row] = 1.f / (1.f + expf(-(s1 + b2[1])));
  }
}

// ---------------- branch driver ----------------
template <int KP>
static void run_branch(const float* x, const int* ei, const int* bat,
                       const float* wc1, const float* bc1, const float* wc2,
                       const float* bc2, const float* fgw1, const float* fgb1,
                       const float* fgw2, const float* fgb2, const float* fgg,
                       const float* fgbt, const float* ffw1, const float* ffb1,
                       const float* ffw2, const float* ffb2, int N, int F,
                       float* out_alpha, float* out_beta, float* out_xg,
                       ushort_t* XB, ushort_t* XA, ushort_t* H, ushort_t* WT,
                       int* deg, int* scanned, int* rowstart, int* cur, int* bsum,
                       int* adj, float* POOL, float* CNT, float* CM, float* MU,
                       float* VAR, float* SSQ, float* G1, float* Z1, float* PART,
                       hipStream_t stream) {
  const int NC = F * 10;
  const int Bn = NGRAPH;
  const int* src = ei;
  const int* dst = ei + EDGES;
  const int MB = (N + 63) / 64;
  const int nb = (N + SCAN_B - 1) / SCAN_B;

  // CSR build
  hipMemsetAsync(deg, 0, (size_t)N * 4, stream);
  hipMemsetAsync(cur, 0, (size_t)N * 4, stream);
  deg_k<<<(EDGES + 255) / 256, 256, 0, stream>>>(dst, deg, EDGES);
  scan_block_k<<<nb, SCAN_B, 0, stream>>>(deg, scanned, bsum, N);
  scan_sums_k<<<1, 512, 0, stream>>>(bsum, nb);
  scan_add_k<<<nb, 256, 0, stream>>>(scanned, bsum, rowstart, N, EDGES);
  fill_k<<<(EDGES + 255) / 256, 256, 0, stream>>>(src, dst, rowstart, cur, adj, EDGES);

  constexpr int CH = KP / 8;
  // x -> bf16 padded
  tobf16_k<KP><<<(int)(((long)N * KP + 255) / 256), 256, 0, stream>>>(x, XB, N, F);
  // conv1
  gather_k<KP><<<(int)(((long)N * CH + 255) / 256), 256, 0, stream>>>(XB, rowstart, adj, XA, N);
  wt_k<<<(((F + 63) / 64) * 64 * KP + 255) / 256, 256, 0, stream>>>(wc1, WT, F, F, KP, ((F + 63) / 64) * 64);
  dim3 g1((F + 63) / 64, MB);
  conv_gemm_k<KP, 0><<<g1, 256, 0, stream>>>(XA, WT, bc1, H, N, F, KP, nullptr, nullptr, 0);
  // conv2 + fused pool
  gather_k<KP><<<(int)(((long)N * CH + 255) / 256), 256, 0, stream>>>(H, rowstart, adj, XA, N);
  int Npad2 = ((NC + 63) / 64) * 64;
  wt_k<<<(Npad2 * KP + 255) / 256, 256, 0, stream>>>(wc2, WT, F, NC, KP, Npad2);
  hipMemsetAsync(POOL, 0, (size_t)Bn * 2 * NC * 4, stream);
  hipMemsetAsync(CNT, 0, Bn * 4, stream);
  dim3 g2(Npad2 / 64, MB);
  conv_gemm_k<KP, 2><<<g2, 256, 0, stream>>>(XA, WT, bc2, nullptr, N, NC, 0, bat, POOL, NC);
  count_k<<<(N + 255) / 256, 256, 0, stream>>>(bat, CNT, N);
  mean_fin_k<<<(Bn * NC + 255) / 256, 256, 0, stream>>>(POOL, CNT, Bn, NC);

  // pairnorm on [Bn, 2*NC]
  int Cols = 2 * NC;
  hipMemsetAsync(SSQ, 0, 8, stream);
  colstat_k<<<(Cols + 63) / 64, 256, 0, stream>>>(POOL, CM, SSQ, Bn, Cols);
  pn_scale_k<<<1, 256, 0, stream>>>(CM, SSQ, SSQ + 1, Bn, Cols);
  pn_apply_k<<<(int)(((long)Bn * Cols + 255) / 256), 256, 0, stream>>>(POOL, CM, SSQ + 1, Bn, Cols);

  // FC1 relu (f32 split-K)
  {
    const int SK = 6;
    int Kc = ((Cols + SK * 16 - 1) / (SK * 16)) * 16;
    gemm_sk_k<<<dim3(1024 / 64, Bn / 64, SK), 256, 0, stream>>>(POOL, fgw1, PART, Bn, Cols, 1024, Kc);
    sk_epi_k<<<(Bn * 1024 + 255) / 256, 256, 0, stream>>>(PART, fgb1, G1, Bn, 1024, SK, 1024, 1);
  }
  // FC2 (no act) -> xg
  {
    const int SK = 4;
    gemm_sk_k<<<dim3(512 / 64, Bn / 64, SK), 256, 0, stream>>>(G1, fgw2, PART, Bn, 1024, 512, 256);
    sk_epi_k<<<(Bn * 512 + 255) / 256, 256, 0, stream>>>(PART, fgb2, out_xg, Bn, 512, SK, 512, 0);
  }
  // batchnorm in place
  bn_stats2_k<<<(512 + 63) / 64, 256, 0, stream>>>(out_xg, MU, VAR, Bn, 512);
  bn_apply_k<<<(Bn * 512 + 255) / 256, 256, 0, stream>>>(out_xg, MU, VAR, fgg, fgbt, Bn, 512);
  // FF1 relu
  {
    const int SK = 8;
    gemm_sk_k<<<dim3(256 / 64, Bn / 64, SK), 256, 0, stream>>>(out_xg, ffw1, PART, Bn, 512, 256, 64);
    sk_epi_k<<<(Bn * 256 + 255) / 256, 256, 0, stream>>>(PART, ffb1, Z1, Bn, 256, SK, 256, 1);
  }
  // FF2 + sigmoid
  ff2_k<<<Bn, 64, 0, stream>>>(Z1, ffw2, ffb2, out_alpha, out_beta, 256);
}

extern "C" void kernel_launch(void* const* d_in, const int* in_sizes, int n_in,
                              void* d_out, int out_size, void* d_ws, size_t ws_size,
                              hipStream_t stream) {
  if (n_in < 34) return;
  const float* x0 = (const float*)d_in[0];
  const int* ei0 = (const int*)d_in[1];
  const int* b0 = (const int*)d_in[2];
  const float* x1 = (const float*)d_in[3];
  const int* ei1 = (const int*)d_in[4];
  const int* b1 = (const int*)d_in[5];
  const float* w_c1 = (const float*)d_in[6];
  const float* b_c1 = (const float*)d_in[7];
  const float* w_c2 = (const float*)d_in[8];
  const float* b_c2 = (const float*)d_in[9];
  const float* w_c3 = (const float*)d_in[10];
  const float* b_c3 = (const float*)d_in[11];
  const float* w_c4 = (const float*)d_in[12];
  const float* b_c4 = (const float*)d_in[13];
  const float* fg0_w1 = (const float*)d_in[14];
  const float* fg0_b1 = (const float*)d_in[15];
  const float* fg0_w2 = (const float*)d_in[16];
  const float* fg0_b2 = (const float*)d_in[17];
  const float* fg0_g = (const float*)d_in[18];
  const float* fg0_bt = (const float*)d_in[19];
  const float* fg1_w1 = (const float*)d_in[20];
  const float* fg1_b1 = (const float*)d_in[21];
  const float* fg1_w2 = (const float*)d_in[22];
  const float* fg1_b2 = (const float*)d_in[23];
  const float* fg1_g = (const float*)d_in[24];
  const float* fg1_bt = (const float*)d_in[25];
  const float* ff0_w1 = (const float*)d_in[26];
  const float* ff0_b1 = (const float*)d_in[27];
  const float* ff0_w2 = (const float*)d_in[28];
  const float* ff0_b2 = (const float*)d_in[29];
  const float* ff1_w1 = (const float*)d_in[30];
  const float* ff1_b1 = (const float*)d_in[31];
  const float* ff1_w2 = (const float*)d_in[32];
  const float* ff1_b2 = (const float*)d_in[33];

  float* out = (float*)d_out;
  float* alpha = out;
  float* beta = out + 1024;
  float* xg0 = out + 2048;
  float* xg1 = out + 2048 + 1024 * 512;
  float* alpha1 = out + 2048 + 2 * 1024 * 512;
  float* beta1 = alpha1 + 1024;

  char* w = (char*)d_ws;
  auto alloc = [&](size_t bytes) -> void* {
    void* p = (void*)w;
    w += ((bytes + 255) / 256) * 256;
    return p;
  };
  const int Mpad = ((NNODES + 63) / 64) * 64;
  ushort_t* XB = (ushort_t*)alloc((size_t)Mpad * 96 * 2);
  ushort_t* XA = (ushort_t*)alloc((size_t)Mpad * 96 * 2);
  ushort_t* H = (ushort_t*)alloc((size_t)Mpad * 96 * 2);
  ushort_t* WT = (ushort_t*)alloc((size_t)960 * 96 * 2);
  int* deg = (int*)alloc((size_t)(NNODES + 1) * 4);
  int* scanned = (int*)alloc((size_t)(NNODES + 1) * 4);
  int* rowstart = (int*)alloc((size_t)(NNODES + 1) * 4);
  int* cur = (int*)alloc((size_t)NNODES * 4);
  int* bsum = (int*)alloc(512 * 4);
  int* adj = (int*)alloc((size_t)EDGES * 4);
  float* POOL = (float*)alloc((size_t)NGRAPH * 1860 * 4);
  float* CNT = (float*)alloc(NGRAPH * 4);
  float* CM = (float*)alloc(1860 * 4);
  float* MU = (float*)alloc(512 * 4);
  float* VAR = (float*)alloc(512 * 4);
  float* SSQ = (float*)alloc(256);
  float* G1 = (float*)alloc((size_t)NGRAPH * 1024 * 4);
  float* Z1 = (float*)alloc((size_t)NGRAPH * 256 * 4);
  if ((size_t)(w - (char*)d_ws) > ws_size) return;

  // PART (split-K partials, up to 6*1024*1024 f32 = 24 MB) aliases XB+XA
  // (dead during the FC phase; branch1's gathers run after branch0's FCs done).
  float* PART = (float*)XB;

  run_branch<96>(x0, ei0, b0, w_c1, b_c1, w_c2, b_c2, fg0_w1, fg0_b1, fg0_w2, fg0_b2,
                 fg0_g, fg0_bt, ff0_w1, ff0_b1, ff0_w2, ff0_b2, NNODES, 93, alpha,
                 beta, xg0, XB, XA, H, WT, deg, scanned, rowstart, cur, bsum, adj,
                 POOL, CNT, CM, MU, VAR, SSQ, G1, Z1, PART, stream);
  run_branch<64>(x1, ei1, b1, w_c3, b_c3, w_c4, b_c4, fg1_w1, fg1_b1, fg1_w2, fg1_b2,
                 fg1_g, fg1_bt, ff1_w1, ff1_b1, ff1_w2, ff1_b2, NNODES, 43, alpha1,
                 beta1, xg1, XB, XA, H, WT, deg, scanned, rowstart, cur, bsum, adj,
                 POOL, CNT, CM, MU, VAR, SSQ, G1, Z1, PART, stream);
}